// Round 2
// baseline (452.934 us; speedup 1.0000x reference)
//
#include <hip/hip_runtime.h>

#define NEXP 10
#define IND 32
#define HD 256
#define OUTD 24
#define OUT2 48
#define BATCH 65536
#define BM 128
#define NTHREADS 512
#define NWAVES 8

typedef _Float16 half8 __attribute__((ext_vector_type(8)));
typedef float f32x4 __attribute__((ext_vector_type(4)));

// workspace layout in halves (total 860160 halves = 1,720,320 bytes):
//   w1p: [E][ct=16][lane=64][8]            = 81920 halves @ 0
//   w2p: [E][kb=8][ct=16][lane=64][8]      = 655360 halves @ 81920
//   w3p: [E][kb=8][ct=3][lane=64][8]       = 122880 halves @ 737280
#define W1P_OFF 0
#define W2P_OFF 81920
#define W3P_OFF 737280
#define PACK_N1 10240          // E*16*64
#define PACK_N2 81920          // E*8*16*64
#define PACK_N3 15360          // E*8*3*64
#define PACK_TOTAL (PACK_N1 + PACK_N2 + PACK_N3)

__device__ __forceinline__ void gl_lds16(const void* g, void* l) {
    __builtin_amdgcn_global_load_lds(
        (const __attribute__((address_space(1))) void*)g,
        (__attribute__((address_space(3))) void*)l, 16, 0, 0);
}

// Pack fp32 weights into f16 MFMA B-fragment order.
// B-frag layout for mfma_f32_16x16x32_f16: lane holds B[k=(lane>>4)*8+j][col=ct*16+(lane&15)]
__global__ void pack_weights(const float* __restrict__ W1,
                             const float* __restrict__ W2,
                             const float* __restrict__ W3,
                             _Float16* __restrict__ wp) {
    int gid = blockIdx.x * blockDim.x + threadIdx.x;
    if (gid >= PACK_TOTAL) return;
    half8 v;
    _Float16* dst;
    if (gid < PACK_N1) {
        int lane = gid & 63, ct = (gid >> 6) & 15, e = gid >> 10;
        int n = ct * 16 + (lane & 15), k0 = (lane >> 4) * 8;
#pragma unroll
        for (int j = 0; j < 8; ++j) v[j] = (_Float16)W1[(e * IND + k0 + j) * HD + n];
        dst = wp + W1P_OFF + gid * 8;
    } else if (gid < PACK_N1 + PACK_N2) {
        int g = gid - PACK_N1;
        int lane = g & 63, ct = (g >> 6) & 15, kb = (g >> 10) & 7, e = g >> 13;
        int n = ct * 16 + (lane & 15), k0 = kb * 32 + (lane >> 4) * 8;
#pragma unroll
        for (int j = 0; j < 8; ++j) v[j] = (_Float16)W2[(e * HD + k0 + j) * HD + n];
        dst = wp + W2P_OFF + g * 8;
    } else {
        int g = gid - (PACK_N1 + PACK_N2);
        int lane = g & 63;
        int t = g >> 6;
        int ct = t % 3, kb = (t / 3) & 7, e = t / 24;
        int n = ct * 16 + (lane & 15), k0 = kb * 32 + (lane >> 4) * 8;
#pragma unroll
        for (int j = 0; j < 8; ++j) v[j] = (_Float16)W3[(e * HD + k0 + j) * OUT2 + n];
        dst = wp + W3P_OFF + g * 8;
    }
    *(half8*)dst = v;
}

__device__ __forceinline__ float silu(float v) {
    return v / (1.0f + __expf(-v));
}

__global__ __launch_bounds__(NTHREADS, 2)
void fused_mlp(const float* __restrict__ x,
               const float* __restrict__ b1,
               const float* __restrict__ b2,
               const float* __restrict__ b3,
               const _Float16* __restrict__ wp,
               float* __restrict__ out) {
    // LDS: 64KB h relayout + 32KB W2 double-buffer + 24KB W3 = 120KB -> 1 block/CU
    __shared__ _Float16 hbuf[NWAVES * 16 * HD];
    __shared__ _Float16 w2buf[2 * 16 * 512];
    __shared__ _Float16 w3buf[24 * 512];

    const int tid = threadIdx.x;
    const int wave = tid >> 6, lane = tid & 63;
    const int l15 = lane & 15, lg = lane >> 4;
    const int e = blockIdx.y;
    const int m0 = blockIdx.x * BM;
    const int wm = m0 + wave * 16;

    const _Float16* w1p = wp + W1P_OFF + e * (16 * 512);
    const _Float16* w2p = wp + W2P_OFF + e * (8 * 16 * 512);
    const _Float16* w3p = wp + W3P_OFF + e * (24 * 512);

    const f32x4 zero = {0.f, 0.f, 0.f, 0.f};

    // ---- stage W3 (24KB) and W2 chunk 0 (16KB) into LDS ----
    // global src is per-lane base + lane*16B; LDS dest is wave-uniform + lane*16B (linear)
#pragma unroll
    for (int it = 0; it < 6; ++it)
        gl_lds16(w3p + it * 4096 + tid * 8, &w3buf[it * 4096 + wave * 512]);
#pragma unroll
    for (int it = 0; it < 2; ++it)
        gl_lds16(w2p + it * 4096 + tid * 8, &w2buf[it * 4096 + wave * 512]);

    // ---- Layer 1: A = x rows (K=32 = exactly one MFMA step) ----
    const float* xr = x + (size_t)(wm + l15) * IND + lg * 8;
    float4 xa = *(const float4*)xr;
    float4 xb = *(const float4*)(xr + 4);
    half8 a1;
    a1[0] = (_Float16)xa.x; a1[1] = (_Float16)xa.y;
    a1[2] = (_Float16)xa.z; a1[3] = (_Float16)xa.w;
    a1[4] = (_Float16)xb.x; a1[5] = (_Float16)xb.y;
    a1[6] = (_Float16)xb.z; a1[7] = (_Float16)xb.w;

    f32x4 acc1[16];
#pragma unroll
    for (int ct = 0; ct < 16; ++ct) {
        half8 b = *(const half8*)(w1p + ct * 512 + lane * 8);
        acc1[ct] = __builtin_amdgcn_mfma_f32_16x16x32_f16(a1, b, zero, 0, 0, 0);
    }

    // bias + silu, store to wave-private LDS slice in A-layout (XOR-swizzled cols)
    _Float16* hb = hbuf + wave * (16 * HD);
#pragma unroll
    for (int ct = 0; ct < 16; ++ct) {
        float bv = b1[e * HD + ct * 16 + l15];
#pragma unroll
        for (int r = 0; r < 4; ++r) {
            int row = lg * 4 + r;
            float v = acc1[ct][r] + bv;
            hb[row * HD + ((ct * 16 + l15) ^ ((row & 7) << 3))] = (_Float16)silu(v);
        }
    }

    // read layer-2 A-fragments (wave-private LDS, in-order ds ops: no barrier needed)
    half8 a2[8];
#pragma unroll
    for (int kb = 0; kb < 8; ++kb) {
        int k0 = kb * 32 + lg * 8;
        a2[kb] = *(const half8*)&hb[l15 * HD + (k0 ^ ((l15 & 7) << 3))];
    }

    f32x4 acc2[16];
#pragma unroll
    for (int ct = 0; ct < 16; ++ct) acc2[ct] = zero;

    __syncthreads();  // W3 + W2 chunk 0 staged (barrier drains vmcnt)

    // ---- Layer 2: K=256 in 8 chunks of 32, LDS double-buffered ----
#pragma unroll
    for (int kb = 0; kb < 8; ++kb) {
        const int cb = kb & 1, nb = (kb + 1) & 1;
        if (kb < 7) {
#pragma unroll
            for (int it = 0; it < 2; ++it)
                gl_lds16(w2p + (kb + 1) * 8192 + it * 4096 + tid * 8,
                         &w2buf[nb * 8192 + it * 4096 + wave * 512]);
        }
        const _Float16* wc = &w2buf[cb * 8192];
#pragma unroll
        for (int ct = 0; ct < 16; ++ct) {
            half8 b = *(const half8*)(wc + ct * 512 + lane * 8);
            acc2[ct] = __builtin_amdgcn_mfma_f32_16x16x32_f16(a2[kb], b, acc2[ct], 0, 0, 0);
        }
        if (kb < 7) __syncthreads();
    }

    // ---- Layer 2 epilogue: bias + silu -> hbuf (overwrite, wave-private) ----
#pragma unroll
    for (int ct = 0; ct < 16; ++ct) {
        float bv = b2[e * HD + ct * 16 + l15];
#pragma unroll
        for (int r = 0; r < 4; ++r) {
            int row = lg * 4 + r;
            float v = acc2[ct][r] + bv;
            hb[row * HD + ((ct * 16 + l15) ^ ((row & 7) << 3))] = (_Float16)silu(v);
        }
    }

    half8 a3[8];
#pragma unroll
    for (int kb = 0; kb < 8; ++kb) {
        int k0 = kb * 32 + lg * 8;
        a3[kb] = *(const half8*)&hb[l15 * HD + (k0 ^ ((l15 & 7) << 3))];
    }

    // ---- Layer 3: 48 outputs = 3 col-tiles ----
    f32x4 acc3[3];
#pragma unroll
    for (int ct = 0; ct < 3; ++ct) acc3[ct] = zero;
#pragma unroll
    for (int ct = 0; ct < 3; ++ct) {
#pragma unroll
        for (int kb = 0; kb < 8; ++kb) {
            half8 b = *(const half8*)&w3buf[(kb * 3 + ct) * 512 + lane * 8];
            acc3[ct] = __builtin_amdgcn_mfma_f32_16x16x32_f16(a3[kb], b, acc3[ct], 0, 0, 0);
        }
    }

    // ---- epilogue: + b3, split means/logvars (out = [means(E,B,24) | logvars(E,B,24)]) ----
#pragma unroll
    for (int ct = 0; ct < 3; ++ct) {
        int col = ct * 16 + l15;
        float bv = b3[e * OUT2 + col];
        size_t obase = (col < OUTD)
            ? ((size_t)e * BATCH * OUTD + (size_t)col)
            : ((size_t)NEXP * BATCH * OUTD + (size_t)e * BATCH * OUTD + (size_t)(col - OUTD));
#pragma unroll
        for (int r = 0; r < 4; ++r) {
            int row = wm + lg * 4 + r;
            out[obase + (size_t)row * OUTD] = acc3[ct][r] + bv;
        }
    }
}

extern "C" void kernel_launch(void* const* d_in, const int* in_sizes, int n_in,
                              void* d_out, int out_size, void* d_ws, size_t ws_size,
                              hipStream_t stream) {
    (void)in_sizes; (void)n_in; (void)out_size; (void)ws_size;
    const float* x  = (const float*)d_in[0];
    const float* W1 = (const float*)d_in[1];
    const float* b1 = (const float*)d_in[2];
    const float* W2 = (const float*)d_in[3];
    const float* b2 = (const float*)d_in[4];
    const float* W3 = (const float*)d_in[5];
    const float* b3 = (const float*)d_in[6];
    float* out = (float*)d_out;
    _Float16* wp = (_Float16*)d_ws;  // needs 1,720,320 bytes

    pack_weights<<<(PACK_TOTAL + 255) / 256, 256, 0, stream>>>(W1, W2, W3, wp);
    dim3 grid(BATCH / BM, NEXP);
    fused_mlp<<<grid, NTHREADS, 0, stream>>>(x, b1, b2, b3, wp, out);
}

// Round 3
// 378.637 us; speedup vs baseline: 1.1962x; 1.1962x over previous
//
#include <hip/hip_runtime.h>

#define NEXP 10
#define IND 32
#define HD 256
#define OUTD 24
#define OUT2 48
#define BATCH 65536
#define NTHREADS 512
#define NWAVES 8
#define ROWS_PER_WAVE 32
#define ROWS_PER_BLOCK 256

typedef _Float16 half8 __attribute__((ext_vector_type(8)));
typedef float f32x16 __attribute__((ext_vector_type(16)));
typedef unsigned int u32;
typedef u32 u32x4 __attribute__((ext_vector_type(4)));

// ---- packed workspace (halves) ----
// w1p: [E][kc=3][mt=8][lane=64][8]   (kc 0,1 = K, kc 2 = bias chunk)
// w2p: [E][kb=17][mt=8][lane=64][8]  (kb 0..15 = K (pi-permuted), 16 = bias)
// w3p: [E][kb=17][mt=2][lane=64][8]  (M padded 48->64; pi-permuted; 16 = bias)
#define W1P_STRIDE 12288     // 3*8*512
#define W2P_STRIDE 69632     // 17*8*512
#define W3P_STRIDE 17408     // 17*2*512
#define W1P_OFF 0
#define W2P_OFF (NEXP * W1P_STRIDE)                  // 122880
#define W3P_OFF (W2P_OFF + NEXP * W2P_STRIDE)        // 819200
#define PACK_PER_E (3*8*64 + 17*8*64 + 17*2*64)      // 12416
#define PACK_TOTAL (NEXP * PACK_PER_E)               // 124160

__device__ __forceinline__ void gl_lds16(const void* g, void* l) {
    __builtin_amdgcn_global_load_lds(
        (const __attribute__((address_space(1))) void*)g,
        (__attribute__((address_space(3))) void*)l, 16, 0, 0);
}

// pi permutation of the K-slot -> hid index (makes D-quads == next B-frags)
__device__ __forceinline__ int pi_map(int kb, int hi, int j) {
    return kb * 16 + hi * 4 + (j & 3) + 8 * (j >> 2);
}

// A-frag (32x32x16, swapped compute): lane holds A[row=lane&31][k=(lane>>5)*8+j]
__global__ void pack_weights(const float* __restrict__ W1, const float* __restrict__ b1,
                             const float* __restrict__ W2, const float* __restrict__ b2,
                             const float* __restrict__ W3, const float* __restrict__ b3,
                             _Float16* __restrict__ wp) {
    int gid = blockIdx.x * blockDim.x + threadIdx.x;
    if (gid >= PACK_TOTAL) return;
    int e = gid / PACK_PER_E;
    int r = gid % PACK_PER_E;
    half8 v;
    _Float16* dst;
    if (r < 1536) {                       // W1^T section
        int kc = r / 512, mt = (r / 64) % 8, lane = r % 64;
        int lo = lane & 31, hi = lane >> 5;
        int n1 = mt * 32 + lo;
#pragma unroll
        for (int j = 0; j < 8; ++j) {
            float x;
            if (kc < 2) { int k = kc * 16 + hi * 8 + j; x = W1[(e * IND + k) * HD + n1]; }
            else        { x = (hi == 0 && j == 0) ? b1[e * HD + n1] : 0.f; }
            v[j] = (_Float16)x;
        }
        dst = wp + W1P_OFF + (size_t)e * W1P_STRIDE + r * 8;
    } else if (r < 1536 + 8704) {         // W2^T section (pi on K)
        int r2 = r - 1536;
        int kb = r2 / 512, mt = (r2 / 64) % 8, lane = r2 % 64;
        int lo = lane & 31, hi = lane >> 5;
        int n2 = mt * 32 + lo;
#pragma unroll
        for (int j = 0; j < 8; ++j) {
            float x;
            if (kb < 16) { int hid = pi_map(kb, hi, j); x = W2[(e * HD + hid) * HD + n2]; }
            else         { x = (hi == 0 && j == 0) ? b2[e * HD + n2] : 0.f; }
            v[j] = (_Float16)x;
        }
        dst = wp + W2P_OFF + (size_t)e * W2P_STRIDE + r2 * 8;
    } else {                              // W3^T section (M padded to 64)
        int r3 = r - 1536 - 8704;
        int kb = r3 / 128, mt = (r3 / 64) % 2, lane = r3 % 64;
        int lo = lane & 31, hi = lane >> 5;
        int n3 = mt * 32 + lo;
#pragma unroll
        for (int j = 0; j < 8; ++j) {
            float x = 0.f;
            if (n3 < OUT2) {
                if (kb < 16) { int hid = pi_map(kb, hi, j); x = W3[(e * HD + hid) * OUT2 + n3]; }
                else         { x = (hi == 0 && j == 0) ? b3[e * OUT2 + n3] : 0.f; }
            }
            v[j] = (_Float16)x;
        }
        dst = wp + W3P_OFF + (size_t)e * W3P_STRIDE + r3 * 8;
    }
    *(half8*)dst = v;
}

__device__ __forceinline__ float silu(float v) {
    return v * __builtin_amdgcn_rcpf(1.0f + __expf(-v));
}

// pack 8 silu'd f32 (elems base..base+7 of acc) into a B-frag half8
__device__ __forceinline__ half8 pack_bfrag(const f32x16& a, int base) {
    float h0 = silu(a[base + 0]), h1 = silu(a[base + 1]);
    float h2 = silu(a[base + 2]), h3 = silu(a[base + 3]);
    float h4 = silu(a[base + 4]), h5 = silu(a[base + 5]);
    float h6 = silu(a[base + 6]), h7 = silu(a[base + 7]);
    u32x4 w;
    w[0] = __builtin_bit_cast(u32, __builtin_amdgcn_cvt_pkrtz(h0, h1));
    w[1] = __builtin_bit_cast(u32, __builtin_amdgcn_cvt_pkrtz(h2, h3));
    w[2] = __builtin_bit_cast(u32, __builtin_amdgcn_cvt_pkrtz(h4, h5));
    w[3] = __builtin_bit_cast(u32, __builtin_amdgcn_cvt_pkrtz(h6, h7));
    return __builtin_bit_cast(half8, w);
}

__global__ __launch_bounds__(NTHREADS, 2)
void fused_mlp(const float* __restrict__ x,
               const _Float16* __restrict__ wp,
               float* __restrict__ out) {
    // LDS: W2 K-chunks 0..15 staged once = 128 KiB. No h buffer, no double-buffer.
    __shared__ _Float16 w2s[128 * 512];

    const int tid = threadIdx.x;
    const int wave = tid >> 6, lane = tid & 63;
    const int lo = lane & 31, hi = lane >> 5;
    const int e = blockIdx.y;
    const int b0 = blockIdx.x * ROWS_PER_BLOCK + wave * ROWS_PER_WAVE;
    const int b = b0 + lo;   // this lane's batch column

    const _Float16* w1pe = wp + W1P_OFF + (size_t)e * W1P_STRIDE;
    const _Float16* w2pe = wp + W2P_OFF + (size_t)e * W2P_STRIDE;
    const _Float16* w2bias = w2pe + 16 * 4096;
    const _Float16* w3pe = wp + W3P_OFF + (size_t)e * W3P_STRIDE;

    // ---- issue W2 staging (16 chunks x 8 mt = 128 x 1KiB; 16 per wave) ----
#pragma unroll
    for (int i = 0; i < 16; ++i) {
        int fid = wave * 16 + i;
        gl_lds16(w2pe + fid * 512 + lane * 8, &w2s[fid * 512]);
    }

    // ---- Layer 1 (overlaps staging): D1 = W1^T x^T, M=256, N=32, K=32+bias ----
    // B-frags from x: kc slot k = kc*16 + hi*8 + j  -> x[b][k]
    const float* xr = x + (size_t)b * IND + hi * 8;
    float4 xa0 = *(const float4*)(xr);
    float4 xa1 = *(const float4*)(xr + 4);
    float4 xb0 = *(const float4*)(xr + 16);
    float4 xb1 = *(const float4*)(xr + 20);
    half8 xf[2];
    {
        u32x4 w;
        w[0] = __builtin_bit_cast(u32, __builtin_amdgcn_cvt_pkrtz(xa0.x, xa0.y));
        w[1] = __builtin_bit_cast(u32, __builtin_amdgcn_cvt_pkrtz(xa0.z, xa0.w));
        w[2] = __builtin_bit_cast(u32, __builtin_amdgcn_cvt_pkrtz(xa1.x, xa1.y));
        w[3] = __builtin_bit_cast(u32, __builtin_amdgcn_cvt_pkrtz(xa1.z, xa1.w));
        xf[0] = __builtin_bit_cast(half8, w);
        w[0] = __builtin_bit_cast(u32, __builtin_amdgcn_cvt_pkrtz(xb0.x, xb0.y));
        w[1] = __builtin_bit_cast(u32, __builtin_amdgcn_cvt_pkrtz(xb0.z, xb0.w));
        w[2] = __builtin_bit_cast(u32, __builtin_amdgcn_cvt_pkrtz(xb1.x, xb1.y));
        w[3] = __builtin_bit_cast(u32, __builtin_amdgcn_cvt_pkrtz(xb1.z, xb1.w));
        xf[1] = __builtin_bit_cast(half8, w);
    }
    // bias-chunk B-frag: slot (hi=0,j=0) = 1.0
    half8 bb;
    {
        u32x4 w = {0u, 0u, 0u, 0u};
        w[0] = (hi == 0) ? 0x00003C00u : 0u;
        bb = __builtin_bit_cast(half8, w);
    }

    f32x16 acc1[8];
#pragma unroll
    for (int mt = 0; mt < 8; ++mt)
#pragma unroll
        for (int i = 0; i < 16; ++i) acc1[mt][i] = 0.f;

#pragma unroll
    for (int kc = 0; kc < 2; ++kc)
#pragma unroll
        for (int mt = 0; mt < 8; ++mt) {
            half8 a = *(const half8*)(w1pe + (kc * 8 + mt) * 512 + lane * 8);
            acc1[mt] = __builtin_amdgcn_mfma_f32_32x32x16_f16(a, xf[kc], acc1[mt], 0, 0, 0);
        }
#pragma unroll
    for (int mt = 0; mt < 8; ++mt) {
        half8 a = *(const half8*)(w1pe + (2 * 8 + mt) * 512 + lane * 8);
        acc1[mt] = __builtin_amdgcn_mfma_f32_32x32x16_f16(a, bb, acc1[mt], 0, 0, 0);
    }

    // ---- L1 epilogue: silu + pack; D-quads ARE L2 B-frags (pi-matched) ----
    half8 bf[16];
#pragma unroll
    for (int kb = 0; kb < 16; ++kb)
        bf[kb] = pack_bfrag(acc1[kb >> 1], (kb & 1) * 8);

    __syncthreads();   // W2 staged (barrier drains vmcnt)

    // ---- Layer 2: D2 = W2^T h1^T, M=256, N=32, K=256+bias ----
    f32x16 acc2[8];
#pragma unroll
    for (int mt = 0; mt < 8; ++mt)
#pragma unroll
        for (int i = 0; i < 16; ++i) acc2[mt][i] = 0.f;

#pragma unroll
    for (int kb = 0; kb < 16; ++kb)
#pragma unroll
        for (int mt = 0; mt < 8; ++mt) {
            half8 a = *(const half8*)&w2s[(kb * 8 + mt) * 512 + lane * 8];
            acc2[mt] = __builtin_amdgcn_mfma_f32_32x32x16_f16(a, bf[kb], acc2[mt], 0, 0, 0);
        }
#pragma unroll
    for (int mt = 0; mt < 8; ++mt) {
        half8 a = *(const half8*)(w2bias + mt * 512 + lane * 8);
        acc2[mt] = __builtin_amdgcn_mfma_f32_32x32x16_f16(a, bb, acc2[mt], 0, 0, 0);
    }

    // ---- L2 epilogue ----
    half8 bf2[16];
#pragma unroll
    for (int kb = 0; kb < 16; ++kb)
        bf2[kb] = pack_bfrag(acc2[kb >> 1], (kb & 1) * 8);

    // ---- Layer 3: D3 = W3^T h2^T, M=64(pad of 48), N=32, K=256+bias ----
    f32x16 acc3[2];
#pragma unroll
    for (int mt = 0; mt < 2; ++mt)
#pragma unroll
        for (int i = 0; i < 16; ++i) acc3[mt][i] = 0.f;

#pragma unroll
    for (int kb = 0; kb < 16; ++kb)
#pragma unroll
        for (int mt = 0; mt < 2; ++mt) {
            half8 a = *(const half8*)(w3pe + (kb * 2 + mt) * 512 + lane * 8);
            acc3[mt] = __builtin_amdgcn_mfma_f32_32x32x16_f16(a, bf2[kb], acc3[mt], 0, 0, 0);
        }
#pragma unroll
    for (int mt = 0; mt < 2; ++mt) {
        half8 a = *(const half8*)(w3pe + (16 * 2 + mt) * 512 + lane * 8);
        acc3[mt] = __builtin_amdgcn_mfma_f32_32x32x16_f16(a, bb, acc3[mt], 0, 0, 0);
    }

    // ---- store: D3 row n = mt*32 + (q*8) + 4*hi + (0..3), col b ----
    const size_t lv_base = (size_t)NEXP * BATCH * OUTD;
#pragma unroll
    for (int mt = 0; mt < 2; ++mt)
#pragma unroll
        for (int q = 0; q < 4; ++q) {
            int n = mt * 32 + q * 8 + 4 * hi;
            if (n >= OUT2) continue;
            float4 v = {acc3[mt][q * 4 + 0], acc3[mt][q * 4 + 1],
                        acc3[mt][q * 4 + 2], acc3[mt][q * 4 + 3]};
            size_t off = (n < OUTD)
                ? (((size_t)e * BATCH + b) * OUTD + n)
                : (lv_base + ((size_t)e * BATCH + b) * OUTD + (n - OUTD));
            *(float4*)&out[off] = v;
        }
}

extern "C" void kernel_launch(void* const* d_in, const int* in_sizes, int n_in,
                              void* d_out, int out_size, void* d_ws, size_t ws_size,
                              hipStream_t stream) {
    (void)in_sizes; (void)n_in; (void)out_size; (void)ws_size;
    const float* x  = (const float*)d_in[0];
    const float* W1 = (const float*)d_in[1];
    const float* b1 = (const float*)d_in[2];
    const float* W2 = (const float*)d_in[3];
    const float* b2 = (const float*)d_in[4];
    const float* W3 = (const float*)d_in[5];
    const float* b3 = (const float*)d_in[6];
    float* out = (float*)d_out;
    _Float16* wp = (_Float16*)d_ws;  // needs 1,986,560 bytes

    pack_weights<<<(PACK_TOTAL + 255) / 256, 256, 0, stream>>>(W1, b1, W2, b2, W3, b3, wp);
    dim3 grid(BATCH / ROWS_PER_BLOCK, NEXP);
    fused_mlp<<<grid, NTHREADS, 0, stream>>>(x, wp, out);
}

// Round 4
// 315.421 us; speedup vs baseline: 1.4360x; 1.2004x over previous
//
#include <hip/hip_runtime.h>

#define NEXP 10
#define IND 32
#define HD 256
#define OUTD 24
#define OUT2 48
#define BATCH 65536
#define NTHREADS 256
#define NWAVES 4
#define ROWS_PER_WAVE 32
#define ROWS_PER_BLOCK 128

typedef _Float16 half8 __attribute__((ext_vector_type(8)));
typedef float f32x16 __attribute__((ext_vector_type(16)));
typedef unsigned int u32;
typedef u32 u32x4 __attribute__((ext_vector_type(4)));

// ---- packed workspace (halves) ---- (IDENTICAL to round-3 validated layout)
// w1p: [E][kc=3][mt=8][lane=64][8]   (kc 0,1 = K, kc 2 = bias chunk)
// w2p: [E][kb=17][mt=8][lane=64][8]  (kb 0..15 = K (pi-permuted), 16 = bias)
// w3p: [E][kb=17][mt=2][lane=64][8]  (M padded 48->64; pi-permuted; 16 = bias)
#define W1P_STRIDE 12288     // 3*8*512
#define W2P_STRIDE 69632     // 17*8*512
#define W3P_STRIDE 17408     // 17*2*512
#define W1P_OFF 0
#define W2P_OFF (NEXP * W1P_STRIDE)                  // 122880
#define W3P_OFF (W2P_OFF + NEXP * W2P_STRIDE)        // 819200
#define PACK_PER_E (3*8*64 + 17*8*64 + 17*2*64)      // 12416
#define PACK_TOTAL (NEXP * PACK_PER_E)               // 124160

__device__ __forceinline__ void gl_lds16(const void* g, void* l) {
    __builtin_amdgcn_global_load_lds(
        (const __attribute__((address_space(1))) void*)g,
        (__attribute__((address_space(3))) void*)l, 16, 0, 0);
}

// pi permutation of the K-slot -> hid index (makes D-quads == next B-frags)
__device__ __forceinline__ int pi_map(int kb, int hi, int j) {
    return kb * 16 + hi * 4 + (j & 3) + 8 * (j >> 2);
}

// A-frag (32x32x16, swapped compute): lane holds A[row=lane&31][k=(lane>>5)*8+j]
__global__ void pack_weights(const float* __restrict__ W1, const float* __restrict__ b1,
                             const float* __restrict__ W2, const float* __restrict__ b2,
                             const float* __restrict__ W3, const float* __restrict__ b3,
                             _Float16* __restrict__ wp) {
    int gid = blockIdx.x * blockDim.x + threadIdx.x;
    if (gid >= PACK_TOTAL) return;
    int e = gid / PACK_PER_E;
    int r = gid % PACK_PER_E;
    half8 v;
    _Float16* dst;
    if (r < 1536) {                       // W1^T section
        int kc = r / 512, mt = (r / 64) % 8, lane = r % 64;
        int lo = lane & 31, hi = lane >> 5;
        int n1 = mt * 32 + lo;
#pragma unroll
        for (int j = 0; j < 8; ++j) {
            float x;
            if (kc < 2) { int k = kc * 16 + hi * 8 + j; x = W1[(e * IND + k) * HD + n1]; }
            else        { x = (hi == 0 && j == 0) ? b1[e * HD + n1] : 0.f; }
            v[j] = (_Float16)x;
        }
        dst = wp + W1P_OFF + (size_t)e * W1P_STRIDE + r * 8;
    } else if (r < 1536 + 8704) {         // W2^T section (pi on K)
        int r2 = r - 1536;
        int kb = r2 / 512, mt = (r2 / 64) % 8, lane = r2 % 64;
        int lo = lane & 31, hi = lane >> 5;
        int n2 = mt * 32 + lo;
#pragma unroll
        for (int j = 0; j < 8; ++j) {
            float x;
            if (kb < 16) { int hid = pi_map(kb, hi, j); x = W2[(e * HD + hid) * HD + n2]; }
            else         { x = (hi == 0 && j == 0) ? b2[e * HD + n2] : 0.f; }
            v[j] = (_Float16)x;
        }
        dst = wp + W2P_OFF + (size_t)e * W2P_STRIDE + r2 * 8;
    } else {                              // W3^T section (M padded to 64)
        int r3 = r - 1536 - 8704;
        int kb = r3 / 128, mt = (r3 / 64) % 2, lane = r3 % 64;
        int lo = lane & 31, hi = lane >> 5;
        int n3 = mt * 32 + lo;
#pragma unroll
        for (int j = 0; j < 8; ++j) {
            float x = 0.f;
            if (n3 < OUT2) {
                if (kb < 16) { int hid = pi_map(kb, hi, j); x = W3[(e * HD + hid) * OUT2 + n3]; }
                else         { x = (hi == 0 && j == 0) ? b3[e * OUT2 + n3] : 0.f; }
            }
            v[j] = (_Float16)x;
        }
        dst = wp + W3P_OFF + (size_t)e * W3P_STRIDE + r3 * 8;
    }
    *(half8*)dst = v;
}

__device__ __forceinline__ float silu(float v) {
    return v * __builtin_amdgcn_rcpf(1.0f + __expf(-v));
}

// pack 8 silu'd f32 (elems base..base+7 of acc) into a B-frag half8
__device__ __forceinline__ half8 pack_bfrag(const f32x16& a, int base) {
    float h0 = silu(a[base + 0]), h1 = silu(a[base + 1]);
    float h2 = silu(a[base + 2]), h3 = silu(a[base + 3]);
    float h4 = silu(a[base + 4]), h5 = silu(a[base + 5]);
    float h6 = silu(a[base + 6]), h7 = silu(a[base + 7]);
    u32x4 w;
    w[0] = __builtin_bit_cast(u32, __builtin_amdgcn_cvt_pkrtz(h0, h1));
    w[1] = __builtin_bit_cast(u32, __builtin_amdgcn_cvt_pkrtz(h2, h3));
    w[2] = __builtin_bit_cast(u32, __builtin_amdgcn_cvt_pkrtz(h4, h5));
    w[3] = __builtin_bit_cast(u32, __builtin_amdgcn_cvt_pkrtz(h6, h7));
    return __builtin_bit_cast(half8, w);
}

// stage one 32 KiB W2 chunk (kb 4c..4c+3) into an LDS buffer; 256 threads x 8 x 16B
__device__ __forceinline__ void stage_chunk(const _Float16* __restrict__ w2pe,
                                            _Float16* dstbuf, int c, int tid) {
    const _Float16* src = w2pe + c * 16384;
#pragma unroll
    for (int i = 0; i < 8; ++i)
        gl_lds16(src + (i * 256 + tid) * 8, dstbuf + (i * 256 + tid) * 8);
}

__global__ __launch_bounds__(NTHREADS, 2)
void fused_mlp(const float* __restrict__ x,
               const _Float16* __restrict__ wp,
               float* __restrict__ out) {
    // LDS: 2 x 32 KiB W2 double-buffer = 64 KiB -> 2 blocks/CU co-resident
    __shared__ _Float16 w2s[2][16384];

    const int tid = threadIdx.x;
    const int wave = tid >> 6, lane = tid & 63;
    const int lo = lane & 31, hi = lane >> 5;
    const int e = blockIdx.y;
    const int b = blockIdx.x * ROWS_PER_BLOCK + wave * ROWS_PER_WAVE + lo;

    const _Float16* w1pe = wp + W1P_OFF + (size_t)e * W1P_STRIDE;
    const _Float16* w2pe = wp + W2P_OFF + (size_t)e * W2P_STRIDE;
    const _Float16* w2bias = w2pe + 16 * 4096;
    const _Float16* w3pe = wp + W3P_OFF + (size_t)e * W3P_STRIDE;

    // ---- issue staging of W2 chunks 0,1 (lands under L1 compute) ----
    stage_chunk(w2pe, w2s[0], 0, tid);
    stage_chunk(w2pe, w2s[1], 1, tid);

    // ---- Layer 1: D1 = W1^T x^T, M=256, N=32, K=32+bias ----
    const float* xr = x + (size_t)b * IND + hi * 8;
    float4 xa0 = *(const float4*)(xr);
    float4 xa1 = *(const float4*)(xr + 4);
    float4 xb0 = *(const float4*)(xr + 16);
    float4 xb1 = *(const float4*)(xr + 20);
    half8 xf[2];
    {
        u32x4 w;
        w[0] = __builtin_bit_cast(u32, __builtin_amdgcn_cvt_pkrtz(xa0.x, xa0.y));
        w[1] = __builtin_bit_cast(u32, __builtin_amdgcn_cvt_pkrtz(xa0.z, xa0.w));
        w[2] = __builtin_bit_cast(u32, __builtin_amdgcn_cvt_pkrtz(xa1.x, xa1.y));
        w[3] = __builtin_bit_cast(u32, __builtin_amdgcn_cvt_pkrtz(xa1.z, xa1.w));
        xf[0] = __builtin_bit_cast(half8, w);
        w[0] = __builtin_bit_cast(u32, __builtin_amdgcn_cvt_pkrtz(xb0.x, xb0.y));
        w[1] = __builtin_bit_cast(u32, __builtin_amdgcn_cvt_pkrtz(xb0.z, xb0.w));
        w[2] = __builtin_bit_cast(u32, __builtin_amdgcn_cvt_pkrtz(xb1.x, xb1.y));
        w[3] = __builtin_bit_cast(u32, __builtin_amdgcn_cvt_pkrtz(xb1.z, xb1.w));
        xf[1] = __builtin_bit_cast(half8, w);
    }
    // bias-chunk B-frag: slot (hi=0,j=0) = 1.0
    half8 bb;
    {
        u32x4 w = {0u, 0u, 0u, 0u};
        w[0] = (hi == 0) ? 0x00003C00u : 0u;
        bb = __builtin_bit_cast(half8, w);
    }

    f32x16 acc1[8];
#pragma unroll
    for (int mt = 0; mt < 8; ++mt)
#pragma unroll
        for (int i = 0; i < 16; ++i) acc1[mt][i] = 0.f;

    __builtin_amdgcn_s_setprio(1);
#pragma unroll
    for (int kc = 0; kc < 2; ++kc)
#pragma unroll
        for (int mt = 0; mt < 8; ++mt) {
            half8 a = *(const half8*)(w1pe + (kc * 8 + mt) * 512 + lane * 8);
            acc1[mt] = __builtin_amdgcn_mfma_f32_32x32x16_f16(a, xf[kc], acc1[mt], 0, 0, 0);
        }
#pragma unroll
    for (int mt = 0; mt < 8; ++mt) {
        half8 a = *(const half8*)(w1pe + (2 * 8 + mt) * 512 + lane * 8);
        acc1[mt] = __builtin_amdgcn_mfma_f32_32x32x16_f16(a, bb, acc1[mt], 0, 0, 0);
    }
    __builtin_amdgcn_s_setprio(0);

    // ---- L1 epilogue: silu + pack; D-quads ARE L2 B-frags (pi-matched) ----
    half8 bf[16];
#pragma unroll
    for (int kb = 0; kb < 16; ++kb)
        bf[kb] = pack_bfrag(acc1[kb >> 1], (kb & 1) * 8);

    f32x16 acc2[8];
#pragma unroll
    for (int mt = 0; mt < 8; ++mt)
#pragma unroll
        for (int i = 0; i < 16; ++i) acc2[mt][i] = 0.f;

    __syncthreads();   // chunks 0,1 staged (barrier drains vmcnt)

    // ---- Layer 2: K=256 as 4 chunks of 4 kb, LDS double-buffered ----
#pragma unroll
    for (int c = 0; c < 4; ++c) {
        const _Float16* buf = w2s[c & 1];
        __builtin_amdgcn_s_setprio(1);
#pragma unroll
        for (int kbl = 0; kbl < 4; ++kbl)
#pragma unroll
            for (int mt = 0; mt < 8; ++mt) {
                half8 a = *(const half8*)(buf + (kbl * 8 + mt) * 512 + lane * 8);
                acc2[mt] = __builtin_amdgcn_mfma_f32_32x32x16_f16(a, bf[c * 4 + kbl], acc2[mt], 0, 0, 0);
            }
        __builtin_amdgcn_s_setprio(0);
        if (c < 3) {
            __syncthreads();               // waves done reading buf; also drains prior stage
            if (c < 2) stage_chunk(w2pe, w2s[c & 1], c + 2, tid);
        }
    }
#pragma unroll
    for (int mt = 0; mt < 8; ++mt) {
        half8 a = *(const half8*)(w2bias + mt * 512 + lane * 8);
        acc2[mt] = __builtin_amdgcn_mfma_f32_32x32x16_f16(a, bb, acc2[mt], 0, 0, 0);
    }

    // ---- L2 epilogue ----
    half8 bf2[16];
#pragma unroll
    for (int kb = 0; kb < 16; ++kb)
        bf2[kb] = pack_bfrag(acc2[kb >> 1], (kb & 1) * 8);

    // ---- Layer 3: D3 = W3^T h2^T, M=64(pad of 48), N=32, K=256+bias ----
    f32x16 acc3[2];
#pragma unroll
    for (int mt = 0; mt < 2; ++mt)
#pragma unroll
        for (int i = 0; i < 16; ++i) acc3[mt][i] = 0.f;

    __builtin_amdgcn_s_setprio(1);
#pragma unroll
    for (int kb = 0; kb < 16; ++kb)
#pragma unroll
        for (int mt = 0; mt < 2; ++mt) {
            half8 a = *(const half8*)(w3pe + (kb * 2 + mt) * 512 + lane * 8);
            acc3[mt] = __builtin_amdgcn_mfma_f32_32x32x16_f16(a, bf2[kb], acc3[mt], 0, 0, 0);
        }
#pragma unroll
    for (int mt = 0; mt < 2; ++mt) {
        half8 a = *(const half8*)(w3pe + (16 * 2 + mt) * 512 + lane * 8);
        acc3[mt] = __builtin_amdgcn_mfma_f32_32x32x16_f16(a, bb, acc3[mt], 0, 0, 0);
    }
    __builtin_amdgcn_s_setprio(0);

    // ---- store: D3 row n = mt*32 + (q*8) + 4*hi + (0..3), col b ----
    const size_t lv_base = (size_t)NEXP * BATCH * OUTD;
#pragma unroll
    for (int mt = 0; mt < 2; ++mt)
#pragma unroll
        for (int q = 0; q < 4; ++q) {
            int n = mt * 32 + q * 8 + 4 * hi;
            if (n >= OUT2) continue;
            float4 v = {acc3[mt][q * 4 + 0], acc3[mt][q * 4 + 1],
                        acc3[mt][q * 4 + 2], acc3[mt][q * 4 + 3]};
            size_t off = (n < OUTD)
                ? (((size_t)e * BATCH + b) * OUTD + n)
                : (lv_base + ((size_t)e * BATCH + b) * OUTD + (n - OUTD));
            *(float4*)&out[off] = v;
        }
}

extern "C" void kernel_launch(void* const* d_in, const int* in_sizes, int n_in,
                              void* d_out, int out_size, void* d_ws, size_t ws_size,
                              hipStream_t stream) {
    (void)in_sizes; (void)n_in; (void)out_size; (void)ws_size;
    const float* x  = (const float*)d_in[0];
    const float* W1 = (const float*)d_in[1];
    const float* b1 = (const float*)d_in[2];
    const float* W2 = (const float*)d_in[3];
    const float* b2 = (const float*)d_in[4];
    const float* W3 = (const float*)d_in[5];
    const float* b3 = (const float*)d_in[6];
    float* out = (float*)d_out;
    _Float16* wp = (_Float16*)d_ws;  // needs 1,986,560 bytes

    pack_weights<<<(PACK_TOTAL + 255) / 256, 256, 0, stream>>>(W1, b1, W2, b2, W3, b3, wp);
    dim3 grid(BATCH / ROWS_PER_BLOCK, NEXP);
    fused_mlp<<<grid, NTHREADS, 0, stream>>>(x, wp, out);
}